// Round 7
// baseline (194.033 us; speedup 1.0000x reference)
//
#include <hip/hip_runtime.h>
#include <stdint.h>

#define B_N   8192
#define D_K   626
#define KPAD  640        // fp8 bytes per row (padded)
#define BK    128        // K-bytes per step (R6-validated optimum)
#define KSTEPS 5         // KPAD / BK
#define BM    128
#define BN    128
#define COL_CHUNKS 16
#define TILES_PER_CHUNK 4   // 8192 / (16*128)
#define FIN_BLOCKS 16

typedef __attribute__((ext_vector_type(4))) int   i32x4;
typedef __attribute__((ext_vector_type(8))) int   i32x8;
typedef __attribute__((ext_vector_type(16))) float f32x16;

__device__ __forceinline__ void async16(const unsigned char* g, unsigned char* l) {
    __builtin_amdgcn_global_load_lds(
        (const __attribute__((address_space(1))) unsigned int*)(const void*)g,
        (__attribute__((address_space(3))) unsigned int*)(void*)l,
        16, 0, 0);
}

// ---------------- Kernel 1: row-normalize + convert to fp8 e4m3 (padded K) --
// R13: 2 rows/wave, 2048 blocks = 8 blocks/CU -> full occupancy.
// (dur_us = gemm + ~76 us additive harness constant, 6 rounds running.)
__global__ __launch_bounds__(256) void normalize_kernel(
    const float* __restrict__ A, const float* __restrict__ P,
    unsigned char* __restrict__ Af8, unsigned char* __restrict__ Pf8,
    float* __restrict__ rowexp, float* __restrict__ rowsum, float* __restrict__ acc)
{
    const int which = blockIdx.y;
    const float* srcM = which ? P : A;
    unsigned char* dstM = which ? Pf8 : Af8;
    const int t  = threadIdx.x;
    const int wv = t >> 6;
    const int L  = t & 63;
    const int rowBase = blockIdx.x * 8 + wv * 2;

    if (which == 0) {
        const int rb = blockIdx.x * 8;
        if (t < 8) { rowexp[rb + t] = 0.0f; rowsum[rb + t] = 0.0f; }
        if (blockIdx.x == 0 && t < 4) acc[t] = 0.0f;   // acc[3] = finalize done-counter
    }

    #pragma unroll
    for (int j = 0; j < 2; ++j) {
        const int r = rowBase + j;
        const float2* s2 = (const float2*)(srcM + (size_t)r * D_K);

        float2 a0 = s2[2 * L];       float2 a1 = s2[2 * L + 1];       // ints 0..63
        float2 b0 = s2[2 * L + 128]; float2 b1 = s2[2 * L + 129];     // ints 64..127
        float2 c0 = {0.f, 0.f},      c1 = {0.f, 0.f};                 // ints 128..159
        if (L < 28)       { c0 = s2[2 * L + 256]; c1 = s2[2 * L + 257]; }
        else if (L == 28) { c0 = s2[312]; }                            // floats 624,625

        float ss = a0.x * a0.x + a0.y * a0.y + a1.x * a1.x + a1.y * a1.y
                 + b0.x * b0.x + b0.y * b0.y + b1.x * b1.x + b1.y * b1.y
                 + c0.x * c0.x + c0.y * c0.y + c1.x * c1.x + c1.y * c1.y;
        #pragma unroll
        for (int off = 32; off; off >>= 1) ss += __shfl_xor(ss, off, 64);
        const float rn = rsqrtf(ss);   // norms ~25, eps never active

        int* d4 = (int*)(dstM + (size_t)r * KPAD);
        int pk0 = __builtin_amdgcn_cvt_pk_fp8_f32(a0.x * rn, a0.y * rn, 0, false);
        pk0 = __builtin_amdgcn_cvt_pk_fp8_f32(a1.x * rn, a1.y * rn, pk0, true);
        d4[L] = pk0;
        int pk1 = __builtin_amdgcn_cvt_pk_fp8_f32(b0.x * rn, b0.y * rn, 0, false);
        pk1 = __builtin_amdgcn_cvt_pk_fp8_f32(b1.x * rn, b1.y * rn, pk1, true);
        d4[L + 64] = pk1;
        if (L < 32) {
            int pk2 = __builtin_amdgcn_cvt_pk_fp8_f32(c0.x * rn, c0.y * rn, 0, false);
            pk2 = __builtin_amdgcn_cvt_pk_fp8_f32(c1.x * rn, c1.y * rn, pk2, true);
            d4[L + 128] = pk2;
        }
    }
}

// ---------------- Kernel 2: fused fp8 cosine-GEMM + row reductions ----------
// R19: B operands DIRECT global->VGPR; A keeps the R14-validated LDS path.
// R18 post-mortem (88.4 us): BK=64 @3 blocks/CU lost; occupancy only 23%.
//   Four schedule/TLP experiments (R15-R18) all lost to R14's 74.7 -> that
//   axis is closed. R13's port arithmetic: LDS data path ~78% busy (8 b128
//   reads + staging writes per wave-step) vs MFMA pipe 24% -> LDS is the
//   critical resource. B's fragment is a CONTIGUOUS 32 B of a Pf8 row ->
//   load it as 2x global_load_dwordx4 (95% L2-hit), skipping LDS entirely:
//   LDS reads halve, staging writes halve, barrier drain covers A only.
// R12 distinction: R12 put the PREFETCH (global_load_lds) behind direct
//   loads in the in-order vmcnt queue. Here direct B loads issue BEFORE the
//   A-stage (sched_barrier(0) pins order), so the compiler's wait before
//   the MFMAs retires only B and leaves A's prefetch in flight; the
//   __syncthreads drain covers A as in R14. Per-lane B bytes are identical
//   to the LDS path -> absmax must be bit-identical.
// Cost: waves sharing wc duplicate B loads (2x B L2 traffic, ~13 TB/s agg,
//   under the 34 TB/s ceiling). LDS 64->32 KB (A dbuf only).
// A-side geometry: R14's HW-VALIDATED zero-conflict swizzle verbatim
//   (8x16B slots/row, key = (rA&7)^((rA>>4)&1), involution on stage source
//   and read, rule #21).
// Ledger (do NOT retry):
//  - R8: forcing occupancy past reg budget -> scratch spill (2x)
//  - R9/R18: BK=64 2-phase (2 or 3 blocks/CU): slower
//  - R10: fused exit-path __threadfence -> L2 writeback storm (2x)
//  - R12: direct-to-reg BEHIND the LDS prefetch in vmcnt queue (2x)
//  - R15: same-B-panel-on-all-XCDs mapping: FETCH 3.6x (2.9x slower)
//  - R16: coarse counted-vmcnt (no per-phase interleave): -17% (m196)
//  - R17: 8-phase port, small MFMA clusters @1 block/CU: -90%
__global__ __launch_bounds__(256, 2) void gemm_fused_kernel(
    const unsigned char* __restrict__ Af8, const unsigned char* __restrict__ Pf8,
    float* __restrict__ rowexp, float* __restrict__ rowsum, float* __restrict__ diag)
{
    __shared__ __align__(16) unsigned char sA[2][BM * BK];   // 32 KB total

    const int t    = threadIdx.x;
    const int lane = t & 63;
    const int w    = t >> 6;
    const int wr   = w >> 1;      // wave row (0..1)
    const int wc   = w & 1;       // wave col (0..1)
    const int rA   = lane & 31;   // row within a 32-row block
    const int h    = lane >> 5;   // K-half selector (which 32 of the 64 k-bytes)
    const int rx   = (rA & 7) ^ ((rA >> 4) & 1);   // R14 swizzle key

    const int rowBase = blockIdx.x * BM;       // 64 row-tiles
    const int chunk   = blockIdx.y;            // 16 col-chunks

    // A staging: 1024 chunks of 16 B, 4 per thread (R14 verbatim, A only)
    const int p0 = t, p1 = t + 256, p2 = t + 512, p3 = t + 768;
    const int r0 = p0 >> 3, r1 = p1 >> 3, r2 = p2 >> 3, r3 = p3 >> 3;
    const size_t g0 = (size_t)r0 * KPAD
                    + (size_t)((((p0 & 7) ^ (r0 & 7) ^ ((r0 >> 4) & 1))) * 16);
    const size_t g1 = (size_t)r1 * KPAD
                    + (size_t)((((p1 & 7) ^ (r1 & 7) ^ ((r1 >> 4) & 1))) * 16);
    const size_t g2 = (size_t)r2 * KPAD
                    + (size_t)((((p2 & 7) ^ (r2 & 7) ^ ((r2 >> 4) & 1))) * 16);
    const size_t g3 = (size_t)r3 * KPAD
                    + (size_t)((((p3 & 7) ^ (r3 & 7) ^ ((r3 >> 4) & 1))) * 16);

    const unsigned char* Ab = Af8 + (size_t)rowBase * KPAD;
    const unsigned char* PbChunk = Pf8 + (size_t)(chunk * TILES_PER_CHUNK) * BN * KPAD;

    // B direct-load row offsets (constant per lane): row wc*64+ni*32+rA,
    // byte h*32 within each 64-B k-block
    const size_t bOff0 = (size_t)(wc * 64 + 0 * 32 + rA) * KPAD + (size_t)(h * 32);
    const size_t bOff1 = (size_t)(wc * 64 + 1 * 32 + rA) * KPAD + (size_t)(h * 32);

    // persistent per-lane row partials: [mi][reg]
    float psum[2][16], pexp[2][16];
    #pragma unroll
    for (int i = 0; i < 2; ++i)
        #pragma unroll
        for (int j = 0; j < 16; ++j) { psum[i][j] = 0.0f; pexp[i][j] = 0.0f; }

    const f32x16 z16 = {0.f,0.f,0.f,0.f,0.f,0.f,0.f,0.f,
                        0.f,0.f,0.f,0.f,0.f,0.f,0.f,0.f};
    f32x16 acc[2][2];   // [mi][ni], each 32x32
    acc[0][0] = z16; acc[0][1] = z16; acc[1][0] = z16; acc[1][1] = z16;

    // prologue: stage A (ks=0) into buffer 0
    async16(Ab + g0, &sA[0][p0 * 16]);
    async16(Ab + g1, &sA[0][p1 * 16]);
    async16(Ab + g2, &sA[0][p2 * 16]);
    async16(Ab + g3, &sA[0][p3 * 16]);

    int par = 0;   // buffer holding the CURRENT step's A tile
    for (int ct = 0; ct < TILES_PER_CHUNK; ++ct) {
        const unsigned char* PbTile = PbChunk + (size_t)ct * BN * KPAD;

        #pragma unroll 1
        for (int ks = 0; ks < KSTEPS; ++ks) {
            __syncthreads();   // buf[par] ready (A loads in flight since last iter)

            // ---- B fragments: direct global->VGPR (issue FIRST in queue) ----
            const unsigned char* pB = PbTile + (size_t)ks * BK;
            i32x4 bLo[2][2], bHi[2][2];    // [kb][ni]
            #pragma unroll
            for (int kb = 0; kb < 2; ++kb) {
                const unsigned char* pK = pB + kb * 64;
                bLo[kb][0] = *(const i32x4*)(pK + bOff0);
                bHi[kb][0] = *(const i32x4*)(pK + bOff0 + 16);
                bLo[kb][1] = *(const i32x4*)(pK + bOff1);
                bHi[kb][1] = *(const i32x4*)(pK + bOff1 + 16);
            }
            __builtin_amdgcn_sched_barrier(0);   // pin: B loads precede A stage

            // ---- issue next step's A staging into buf[par^1] ----
            int nks = ks + 1, nct = ct;
            if (nks == KSTEPS) { nks = 0; ++nct; }
            if (nct < TILES_PER_CHUNK) {
                const int nxt = par ^ 1;
                const unsigned char* AbN = Ab + (size_t)nks * BK;
                async16(AbN + g0, &sA[nxt][p0 * 16]);
                async16(AbN + g1, &sA[nxt][p1 * 16]);
                async16(AbN + g2, &sA[nxt][p2 * 16]);
                async16(AbN + g3, &sA[nxt][p3 * 16]);
            }

            // ---- compute from buf[par] (A via LDS) + B regs ----
            #pragma unroll
            for (int kb = 0; kb < 2; ++kb) {
                const int c0 = kb * 4 + 2 * h;              // logical 16B chunk pair
                const int s0 = ((c0    ) ^ rx) * 16;        // physical (swizzled)
                const int s1 = ((c0 ^ 1) ^ rx) * 16;

                i32x8 aF[2], bF[2];
                #pragma unroll
                for (int mi = 0; mi < 2; ++mi) {
                    const unsigned char* base = &sA[par][(wr * 64 + mi * 32 + rA) * BK];
                    i32x4 lo = *(const i32x4*)(base + s0);
                    i32x4 hi = *(const i32x4*)(base + s1);
                    aF[mi] = __builtin_shufflevector(lo, hi, 0, 1, 2, 3, 4, 5, 6, 7);
                }
                bF[0] = __builtin_shufflevector(bLo[kb][0], bHi[kb][0],
                                                0, 1, 2, 3, 4, 5, 6, 7);
                bF[1] = __builtin_shufflevector(bLo[kb][1], bHi[kb][1],
                                                0, 1, 2, 3, 4, 5, 6, 7);

                #pragma unroll
                for (int mi = 0; mi < 2; ++mi)
                    #pragma unroll
                    for (int ni = 0; ni < 2; ++ni)
                        acc[mi][ni] = __builtin_amdgcn_mfma_scale_f32_32x32x64_f8f6f4(
                            aF[mi], bF[ni], acc[mi][ni],
                            0 /*A: fp8 e4m3*/, 0 /*B: fp8 e4m3*/,
                            0, 0x7F /*scaleA=2^0*/, 0, 0x7F /*scaleB=2^0*/);
            }
            par ^= 1;
        }

        // ----- per-ct epilogue (registers only, no LDS -> no barrier) -----
        const int colBase = (chunk * TILES_PER_CHUNK + ct) * BN;

        // C/D layout: col = rA, row = (rg&3) + 8*(rg>>2) + 4*h  (verified R13-R18)
        if (rowBase == colBase && wr == wc) {   // diagonal tile: rare, uniform
            #pragma unroll
            for (int mi = 0; mi < 2; ++mi)
                #pragma unroll
                for (int rg = 0; rg < 16; ++rg) {
                    const int row32 = (rg & 3) + 8 * (rg >> 2) + 4 * h;
                    if (rA == row32)
                        diag[rowBase + wr * 64 + mi * 32 + row32] = acc[mi][mi][rg];
                }
        }

        #pragma unroll
        for (int mi = 0; mi < 2; ++mi) {
            #pragma unroll
            for (int rg = 0; rg < 16; ++rg) {
                const float S0 = acc[mi][0][rg];
                const float S1 = acc[mi][1][rg];
                psum[mi][rg] += S0 + S1;
                pexp[mi][rg] += __expf(S0 * 4.0f) + __expf(S1 * 4.0f);  // logits=S/0.25
            }
        }
        acc[0][0] = z16; acc[0][1] = z16; acc[1][0] = z16; acc[1][1] = z16;
    }

    // reduce across the 32 columns (rA lanes; offsets <=16 preserve the h bit)
    #pragma unroll
    for (int off = 1; off <= 16; off <<= 1) {
        #pragma unroll
        for (int mi = 0; mi < 2; ++mi)
            #pragma unroll
            for (int rg = 0; rg < 16; ++rg) {
                psum[mi][rg] += __shfl_xor(psum[mi][rg], off, 64);
                pexp[mi][rg] += __shfl_xor(pexp[mi][rg], off, 64);
            }
    }
    if (rA == 0) {   // lanes 0 and 32 hold the h=0 / h=1 row groups
        #pragma unroll
        for (int mi = 0; mi < 2; ++mi)
            #pragma unroll
            for (int rg = 0; rg < 16; ++rg) {
                const int gr = rowBase + wr * 64 + mi * 32
                             + (rg & 3) + 8 * (rg >> 2) + 4 * h;
                atomicAdd(&rowsum[gr], psum[mi][rg]);
                atomicAdd(&rowexp[gr], pexp[mi][rg]);
            }
    }
}

// ---------------- Kernel 3: final reduction + device-side completion --------
__global__ __launch_bounds__(256) void finalize_kernel(
    const float* __restrict__ rowexp, const float* __restrict__ rowsum,
    const float* __restrict__ diag, float* __restrict__ acc, float* __restrict__ out)
{
    const int t = threadIdx.x;
    float ls = 0.f, ds = 0.f, ns = 0.f;
    for (int i = blockIdx.x * 256 + t; i < B_N; i += FIN_BLOCKS * 256) {
        const float d = diag[i];
        ls += __logf(rowexp[i]) - d * 4.0f;   // logsumexp - diag_logit
        ds += d;
        ns += (rowsum[i] - d);
    }
    #pragma unroll
    for (int off = 32; off; off >>= 1) {
        ls += __shfl_down(ls, off, 64);
        ds += __shfl_down(ds, off, 64);
        ns += __shfl_down(ns, off, 64);
    }
    __shared__ float sl[4], sd[4], sn[4];
    if ((t & 63) == 0) { sl[t >> 6] = ls; sd[t >> 6] = ds; sn[t >> 6] = ns; }
    __syncthreads();
    if (t == 0) {
        atomicAdd(acc + 0, sl[0] + sl[1] + sl[2] + sl[3]);
        atomicAdd(acc + 1, sd[0] + sd[1] + sd[2] + sd[3]);
        atomicAdd(acc + 2, sn[0] + sn[1] + sn[2] + sn[3]);
        __threadfence();
        const int done = (int)atomicAdd((unsigned int*)(acc + 3), 1u);
        if (done == FIN_BLOCKS - 1) {
            const float L  = atomicAdd(acc + 0, 0.0f);   // coherent reads
            const float Dm = atomicAdd(acc + 1, 0.0f);
            const float Nn = atomicAdd(acc + 2, 0.0f);
            out[0] = L / (float)B_N;
            out[1] = Dm / (float)B_N;
            out[2] = (Nn / (float)(B_N - 1)) / (float)B_N;
        }
    }
}

// ---------------- Fallback path (small workspace): fp32 vector --------------
__global__ __launch_bounds__(256) void fb_norm(
    const float* __restrict__ A, const float* __restrict__ P,
    float* __restrict__ rna, float* __restrict__ rnp, float* __restrict__ acc)
{
    const int r = blockIdx.x;
    const float* src = blockIdx.y ? P : A;
    const int t = threadIdx.x;
    float ss = 0.f;
    for (int k = t; k < D_K; k += 256) { float v = src[(size_t)r * D_K + k]; ss += v * v; }
    #pragma unroll
    for (int off = 32; off; off >>= 1) ss += __shfl_down(ss, off, 64);
    __shared__ float sred[4];
    if ((t & 63) == 0) sred[t >> 6] = ss;
    __syncthreads();
    if (t == 0) {
        const float rn = rsqrtf(sred[0] + sred[1] + sred[2] + sred[3]);
        (blockIdx.y ? rnp : rna)[r] = rn;
    }
    if (blockIdx.x == 0 && blockIdx.y == 0 && t < 3) acc[t] = 0.0f;
}

__global__ __launch_bounds__(256) void fb_main(
    const float* __restrict__ A, const float* __restrict__ P,
    const float* __restrict__ rna, const float* __restrict__ rnp,
    float* __restrict__ acc)
{
    __shared__ float sa[D_K];
    __shared__ float red[12];
    const int i = blockIdx.x;
    const int t = threadIdx.x;
    const float rn = rna[i];
    for (int k = t; k < D_K; k += 256) sa[k] = A[(size_t)i * D_K + k] * rn;
    __syncthreads();
    const int w = t >> 6, lane = t & 63;
    float we = 0.f, wsum = 0.f, wd = 0.f;
    for (int j = w; j < B_N; j += 4) {
        float dot = 0.f;
        const float* p = P + (size_t)j * D_K;
        for (int k = lane; k < D_K; k += 64) dot += sa[k] * p[k];
        #pragma unroll
        for (int off = 32; off; off >>= 1) dot += __shfl_xor(dot, off, 64);
        const float S = dot * rnp[j];
        we += __expf(S * 4.0f);
        wsum += S;
        if (j == i) wd = S;
    }
    if (lane == 0) { red[w] = we; red[4 + w] = wsum; red[8 + w] = wd; }
    __syncthreads();
    if (t == 0) {
        const float E  = red[0] + red[1] + red[2] + red[3];
        const float Sm = red[4] + red[5] + red[6] + red[7];
        const float Dd = red[8] + red[9] + red[10] + red[11];
        atomicAdd(acc + 0, __logf(E) - 4.0f * Dd);
        atomicAdd(acc + 1, Dd);
        atomicAdd(acc + 2, Sm - Dd);
    }
}

__global__ void fb_fin(const float* __restrict__ acc, float* __restrict__ out)
{
    out[0] = acc[0] / (float)B_N;
    out[1] = acc[1] / (float)B_N;
    out[2] = acc[2] / ((float)(B_N - 1) * (float)B_N);
}

// ---------------------------------------------------------------------------
extern "C" void kernel_launch(void* const* d_in, const int* in_sizes, int n_in,
                              void* d_out, int out_size, void* d_ws, size_t ws_size,
                              hipStream_t stream)
{
    const float* A = (const float*)d_in[0];
    const float* P = (const float*)d_in[1];
    float* out = (float*)d_out;
    char* ws = (char*)d_ws;

    const size_t AF8_OFF  = 0;
    const size_t PF8_OFF  = AF8_OFF + (size_t)B_N * KPAD;
    const size_t REXP_OFF = PF8_OFF + (size_t)B_N * KPAD;
    const size_t RSUM_OFF = REXP_OFF + (size_t)B_N * sizeof(float);
    const size_t DIAG_OFF = RSUM_OFF + (size_t)B_N * sizeof(float);
    const size_t ACC_OFF  = DIAG_OFF + (size_t)B_N * sizeof(float);
    const size_t MAIN_REQ = ACC_OFF + 16;

    if (ws_size >= MAIN_REQ) {
        unsigned char* Af8 = (unsigned char*)(ws + AF8_OFF);
        unsigned char* Pf8 = (unsigned char*)(ws + PF8_OFF);
        float* rowexp = (float*)(ws + REXP_OFF);
        float* rowsum = (float*)(ws + RSUM_OFF);
        float* diag   = (float*)(ws + DIAG_OFF);
        float* acc    = (float*)(ws + ACC_OFF);

        normalize_kernel<<<dim3(B_N / 8, 2), 256, 0, stream>>>(A, P, Af8, Pf8,
                                                               rowexp, rowsum, acc);
        gemm_fused_kernel<<<dim3(B_N / BM, COL_CHUNKS), 256, 0, stream>>>(
            Af8, Pf8, rowexp, rowsum, diag);
        finalize_kernel<<<FIN_BLOCKS, 256, 0, stream>>>(rowexp, rowsum, diag, acc, out);
    } else {
        // slow-but-correct fp32 fallback (needs ~96 KB ws)
        float* rna = (float*)ws;
        float* rnp = rna + B_N;
        float* acc = rnp + B_N;
        fb_norm<<<dim3(B_N, 2), 256, 0, stream>>>(A, P, rna, rnp, acc);
        fb_main<<<B_N, 256, 0, stream>>>(A, P, rna, rnp, acc);
        fb_fin<<<1, 1, 0, stream>>>(acc, out);
    }
}

// Round 8
// 150.316 us; speedup vs baseline: 1.2908x; 1.2908x over previous
//
#include <hip/hip_runtime.h>
#include <stdint.h>

#define B_N   8192
#define D_K   626
#define KPAD  640        // fp8 bytes per row (padded)
#define BK    128        // K-bytes per step (R6-validated optimum)
#define KSTEPS 5         // KPAD / BK
#define BM    128
#define BN    128
#define COL_CHUNKS 16
#define TILES_PER_CHUNK 4   // 8192 / (16*128)
#define FIN_BLOCKS 16

typedef __attribute__((ext_vector_type(4))) float f32x4;
typedef __attribute__((ext_vector_type(4))) int   i32x4;
typedef __attribute__((ext_vector_type(8))) int   i32x8;
typedef __attribute__((ext_vector_type(16))) float f32x16;

__device__ __forceinline__ void async16(const unsigned char* g, unsigned char* l) {
    __builtin_amdgcn_global_load_lds(
        (const __attribute__((address_space(1))) unsigned int*)(const void*)g,
        (__attribute__((address_space(3))) unsigned int*)(void*)l,
        16, 0, 0);
}

// ---------------- Kernel 1: row-normalize + convert to fp8 e4m3 (padded K) --
// R13: 2 rows/wave, 2048 blocks = 8 blocks/CU -> full occupancy.
// (dur_us = gemm + ~76 us additive harness constant, 7 rounds running.)
__global__ __launch_bounds__(256) void normalize_kernel(
    const float* __restrict__ A, const float* __restrict__ P,
    unsigned char* __restrict__ Af8, unsigned char* __restrict__ Pf8,
    float* __restrict__ rowexp, float* __restrict__ rowsum, float* __restrict__ acc)
{
    const int which = blockIdx.y;
    const float* srcM = which ? P : A;
    unsigned char* dstM = which ? Pf8 : Af8;
    const int t  = threadIdx.x;
    const int wv = t >> 6;
    const int L  = t & 63;
    const int rowBase = blockIdx.x * 8 + wv * 2;

    if (which == 0) {
        const int rb = blockIdx.x * 8;
        if (t < 8) { rowexp[rb + t] = 0.0f; rowsum[rb + t] = 0.0f; }
        if (blockIdx.x == 0 && t < 4) acc[t] = 0.0f;   // acc[3] = finalize done-counter
    }

    #pragma unroll
    for (int j = 0; j < 2; ++j) {
        const int r = rowBase + j;
        const float2* s2 = (const float2*)(srcM + (size_t)r * D_K);

        float2 a0 = s2[2 * L];       float2 a1 = s2[2 * L + 1];       // ints 0..63
        float2 b0 = s2[2 * L + 128]; float2 b1 = s2[2 * L + 129];     // ints 64..127
        float2 c0 = {0.f, 0.f},      c1 = {0.f, 0.f};                 // ints 128..159
        if (L < 28)       { c0 = s2[2 * L + 256]; c1 = s2[2 * L + 257]; }
        else if (L == 28) { c0 = s2[312]; }                            // floats 624,625

        float ss = a0.x * a0.x + a0.y * a0.y + a1.x * a1.x + a1.y * a1.y
                 + b0.x * b0.x + b0.y * b0.y + b1.x * b1.x + b1.y * b1.y
                 + c0.x * c0.x + c0.y * c0.y + c1.x * c1.x + c1.y * c1.y;
        #pragma unroll
        for (int off = 32; off; off >>= 1) ss += __shfl_xor(ss, off, 64);
        const float rn = rsqrtf(ss);   // norms ~25, eps never active

        int* d4 = (int*)(dstM + (size_t)r * KPAD);
        int pk0 = __builtin_amdgcn_cvt_pk_fp8_f32(a0.x * rn, a0.y * rn, 0, false);
        pk0 = __builtin_amdgcn_cvt_pk_fp8_f32(a1.x * rn, a1.y * rn, pk0, true);
        d4[L] = pk0;
        int pk1 = __builtin_amdgcn_cvt_pk_fp8_f32(b0.x * rn, b0.y * rn, 0, false);
        pk1 = __builtin_amdgcn_cvt_pk_fp8_f32(b1.x * rn, b1.y * rn, pk1, true);
        d4[L + 64] = pk1;
        if (L < 32) {
            int pk2 = __builtin_amdgcn_cvt_pk_fp8_f32(c0.x * rn, c0.y * rn, 0, false);
            pk2 = __builtin_amdgcn_cvt_pk_fp8_f32(c1.x * rn, c1.y * rn, pk2, true);
            d4[L + 128] = pk2;
        }
    }
}

// ---------------- Kernel 2: fused fp8 cosine-GEMM + row reductions ----------
// R20: PURE REVERT to the R14 configuration (session best: gemm 74.5-76.1 us
// measured 3x across two machines; dur_us 150.7). MX-scaled fp8 32x32x64
// MFMA + row-bit4-augmented XOR swizzle (0 bank conflicts) + BK=128
// double-buffer, ONE barrier per K-step, launch_bounds(256,2).
// SESSION VERDICT (R13-R19): the ~55% drain stall in this 2-phase loop is
// structurally protected by in-order vmcnt + barrier-drain semantics.
// Closed ledger (do NOT retry):
//  - R8:  min-waves=4 -> forced 64 VGPR -> scratch spill (2x slower)
//  - R9:  BK=64 @2 blocks/CU under drain-per-barrier (2x slower)
//  - R10: fused exit-path __threadfence -> L2 writeback storm (2x slower)
//  - R12: A direct global->VGPR behind LDS prefetch in vmcnt queue (2x)
//  - R14: swizzle alone under 2-phase drain: conflicts 5.24M->0, time ~0
//    (regime-gated; kept because it is free and validated)
//  - R15: 256^2 + 1 block/CU + same-B-panel-on-all-XCDs: FETCH 3.6x (2.9x)
//  - R16: coarse counted-vmcnt, no per-phase interleave: -17% (m196 class)
//  - R17: 8-phase port, 4-MFMA clusters @1 block/CU: -90% (MfmaUtil 11.7%)
//  - R18: BK=64 @3 blocks/CU: occupancy 23% not 30%, -18%
//  - R19: B direct global->VGPR, no prefetch: per-step L2 latency exposed
//    serially + 32-line strided loads, -60% (MfmaUtil 14%)
__global__ __launch_bounds__(256, 2) void gemm_fused_kernel(
    const unsigned char* __restrict__ Af8, const unsigned char* __restrict__ Pf8,
    float* __restrict__ rowexp, float* __restrict__ rowsum, float* __restrict__ diag)
{
    __shared__ __align__(16) unsigned char sA[2][BM * BK];   // 32 KB
    __shared__ __align__(16) unsigned char sB[2][BN * BK];   // 32 KB

    const int t    = threadIdx.x;
    const int lane = t & 63;
    const int w    = t >> 6;
    const int wr   = w >> 1;      // wave row (0..1)
    const int wc   = w & 1;       // wave col (0..1)
    const int rA   = lane & 31;   // row within a 32-row block
    const int h    = lane >> 5;   // K-half selector (which 32 of the 64 k-bytes)
    const int rx   = (rA & 7) ^ ((rA >> 4) & 1);   // R14 swizzle key (bits 0-2 ^ bit4)

    const int rowBase = blockIdx.x * BM;       // 64 row-tiles
    const int chunk   = blockIdx.y;            // 16 col-chunks

    // staging: per matrix 1024 chunks of 16 B, 4 per thread (p = t + j*256)
    // source pre-swizzle includes row bit 4 (matches read side; rule #21)
    const int p0 = t, p1 = t + 256, p2 = t + 512, p3 = t + 768;
    const int r0 = p0 >> 3, r1 = p1 >> 3, r2 = p2 >> 3, r3 = p3 >> 3;
    const size_t g0 = (size_t)r0 * KPAD
                    + (size_t)((((p0 & 7) ^ (r0 & 7) ^ ((r0 >> 4) & 1))) * 16);
    const size_t g1 = (size_t)r1 * KPAD
                    + (size_t)((((p1 & 7) ^ (r1 & 7) ^ ((r1 >> 4) & 1))) * 16);
    const size_t g2 = (size_t)r2 * KPAD
                    + (size_t)((((p2 & 7) ^ (r2 & 7) ^ ((r2 >> 4) & 1))) * 16);
    const size_t g3 = (size_t)r3 * KPAD
                    + (size_t)((((p3 & 7) ^ (r3 & 7) ^ ((r3 >> 4) & 1))) * 16);

    const unsigned char* Ab = Af8 + (size_t)rowBase * KPAD;
    const unsigned char* PbChunk = Pf8 + (size_t)(chunk * TILES_PER_CHUNK) * BN * KPAD;

    // persistent per-lane row partials: [mi][reg]
    float psum[2][16], pexp[2][16];
    #pragma unroll
    for (int i = 0; i < 2; ++i)
        #pragma unroll
        for (int j = 0; j < 16; ++j) { psum[i][j] = 0.0f; pexp[i][j] = 0.0f; }

    const f32x16 z16 = {0.f,0.f,0.f,0.f,0.f,0.f,0.f,0.f,
                        0.f,0.f,0.f,0.f,0.f,0.f,0.f,0.f};
    f32x16 acc[2][2];   // [mi][ni], each 32x32
    acc[0][0] = z16; acc[0][1] = z16; acc[1][0] = z16; acc[1][1] = z16;

    // prologue: stage (ct=0, ks=0) into buffer 0
    {
        async16(Ab + g0, &sA[0][p0 * 16]);
        async16(Ab + g1, &sA[0][p1 * 16]);
        async16(Ab + g2, &sA[0][p2 * 16]);
        async16(Ab + g3, &sA[0][p3 * 16]);
        async16(PbChunk + g0, &sB[0][p0 * 16]);
        async16(PbChunk + g1, &sB[0][p1 * 16]);
        async16(PbChunk + g2, &sB[0][p2 * 16]);
        async16(PbChunk + g3, &sB[0][p3 * 16]);
    }

    int par = 0;   // buffer holding the CURRENT iteration's tiles
    for (int ct = 0; ct < TILES_PER_CHUNK; ++ct) {
        #pragma unroll 1
        for (int ks = 0; ks < KSTEPS; ++ks) {
            __syncthreads();   // buf[par] ready (loads in flight since last iter)

            // issue next iteration's staging into buf[par^1]
            int nks = ks + 1, nct = ct;
            if (nks == KSTEPS) { nks = 0; ++nct; }
            if (nct < TILES_PER_CHUNK) {
                const int nxt = par ^ 1;
                const size_t nkOff = (size_t)nks * BK;
                const unsigned char* PbN = PbChunk + (size_t)nct * BN * KPAD + nkOff;
                const unsigned char* AbN = Ab + nkOff;
                async16(AbN + g0, &sA[nxt][p0 * 16]);
                async16(AbN + g1, &sA[nxt][p1 * 16]);
                async16(AbN + g2, &sA[nxt][p2 * 16]);
                async16(AbN + g3, &sA[nxt][p3 * 16]);
                async16(PbN + g0, &sB[nxt][p0 * 16]);
                async16(PbN + g1, &sB[nxt][p1 * 16]);
                async16(PbN + g2, &sB[nxt][p2 * 16]);
                async16(PbN + g3, &sB[nxt][p3 * 16]);
            }

            // compute from buf[par]: 2 K-blocks of 64 bytes each
            #pragma unroll
            for (int kb = 0; kb < 2; ++kb) {
                const int c0 = kb * 4 + 2 * h;              // logical 16B chunk pair
                const int s0 = ((c0    ) ^ rx) * 16;        // physical (swizzled)
                const int s1 = ((c0 ^ 1) ^ rx) * 16;        // c0 even -> c0+1 == c0^1

                i32x8 aF[2], bF[2];
                #pragma unroll
                for (int mi = 0; mi < 2; ++mi) {
                    const unsigned char* base = &sA[par][(wr * 64 + mi * 32 + rA) * BK];
                    i32x4 lo = *(const i32x4*)(base + s0);
                    i32x4 hi = *(const i32x4*)(base + s1);
                    aF[mi] = __builtin_shufflevector(lo, hi, 0, 1, 2, 3, 4, 5, 6, 7);
                }
                #pragma unroll
                for (int ni = 0; ni < 2; ++ni) {
                    const unsigned char* base = &sB[par][(wc * 64 + ni * 32 + rA) * BK];
                    i32x4 lo = *(const i32x4*)(base + s0);
                    i32x4 hi = *(const i32x4*)(base + s1);
                    bF[ni] = __builtin_shufflevector(lo, hi, 0, 1, 2, 3, 4, 5, 6, 7);
                }

                #pragma unroll
                for (int mi = 0; mi < 2; ++mi)
                    #pragma unroll
                    for (int ni = 0; ni < 2; ++ni)
                        acc[mi][ni] = __builtin_amdgcn_mfma_scale_f32_32x32x64_f8f6f4(
                            aF[mi], bF[ni], acc[mi][ni],
                            0 /*A fmt: fp8 e4m3*/, 0 /*B fmt: fp8 e4m3*/,
                            0, 0x7F /*scale A = 2^0*/, 0, 0x7F /*scale B = 2^0*/);
            }
            par ^= 1;
        }

        // ----- per-ct epilogue (registers only, no LDS -> no barrier) -----
        const int colBase = (chunk * TILES_PER_CHUNK + ct) * BN;

        if (rowBase == colBase && wr == wc) {   // diagonal tile: rare, uniform
            #pragma unroll
            for (int mi = 0; mi < 2; ++mi)
                #pragma unroll
                for (int rg = 0; rg < 16; ++rg) {
                    const int row32 = (rg & 3) + 8 * (rg >> 2) + 4 * h;
                    if (rA == row32)
                        diag[rowBase + wr * 64 + mi * 32 + row32] = acc[mi][mi][rg];
                }
        }

        // C/D layout: col = rA (lane&31), row = (rg&3) + 8*(rg>>2) + 4*h
        #pragma unroll
        for (int mi = 0; mi < 2; ++mi) {
            #pragma unroll
            for (int rg = 0; rg < 16; ++rg) {
                const float S0 = acc[mi][0][rg];
                const float S1 = acc[mi][1][rg];
                psum[mi][rg] += S0 + S1;
                pexp[mi][rg] += __expf(S0 * 4.0f) + __expf(S1 * 4.0f);  // logits = S/0.25
            }
        }
        acc[0][0] = z16; acc[0][1] = z16; acc[1][0] = z16; acc[1][1] = z16;
    }

    // reduce across the 32 columns (rA lanes; offsets <=16 preserve the h bit)
    #pragma unroll
    for (int off = 1; off <= 16; off <<= 1) {
        #pragma unroll
        for (int mi = 0; mi < 2; ++mi)
            #pragma unroll
            for (int rg = 0; rg < 16; ++rg) {
                psum[mi][rg] += __shfl_xor(psum[mi][rg], off, 64);
                pexp[mi][rg] += __shfl_xor(pexp[mi][rg], off, 64);
            }
    }
    if (rA == 0) {   // lanes 0 and 32 hold the h=0 / h=1 row groups
        #pragma unroll
        for (int mi = 0; mi < 2; ++mi)
            #pragma unroll
            for (int rg = 0; rg < 16; ++rg) {
                const int gr = rowBase + wr * 64 + mi * 32
                             + (rg & 3) + 8 * (rg >> 2) + 4 * h;
                atomicAdd(&rowsum[gr], psum[mi][rg]);
                atomicAdd(&rowexp[gr], pexp[mi][rg]);
            }
    }
}

// ---------------- Kernel 3: final reduction + device-side completion --------
__global__ __launch_bounds__(256) void finalize_kernel(
    const float* __restrict__ rowexp, const float* __restrict__ rowsum,
    const float* __restrict__ diag, float* __restrict__ acc, float* __restrict__ out)
{
    const int t = threadIdx.x;
    float ls = 0.f, ds = 0.f, ns = 0.f;
    for (int i = blockIdx.x * 256 + t; i < B_N; i += FIN_BLOCKS * 256) {
        const float d = diag[i];
        ls += __logf(rowexp[i]) - d * 4.0f;   // logsumexp - diag_logit
        ds += d;
        ns += (rowsum[i] - d);
    }
    #pragma unroll
    for (int off = 32; off; off >>= 1) {
        ls += __shfl_down(ls, off, 64);
        ds += __shfl_down(ds, off, 64);
        ns += __shfl_down(ns, off, 64);
    }
    __shared__ float sl[4], sd[4], sn[4];
    if ((t & 63) == 0) { sl[t >> 6] = ls; sd[t >> 6] = ds; sn[t >> 6] = ns; }
    __syncthreads();
    if (t == 0) {
        atomicAdd(acc + 0, sl[0] + sl[1] + sl[2] + sl[3]);
        atomicAdd(acc + 1, sd[0] + sd[1] + sd[2] + sd[3]);
        atomicAdd(acc + 2, sn[0] + sn[1] + sn[2] + sn[3]);
        __threadfence();
        const int done = (int)atomicAdd((unsigned int*)(acc + 3), 1u);
        if (done == FIN_BLOCKS - 1) {
            const float L  = atomicAdd(acc + 0, 0.0f);   // coherent reads
            const float Dm = atomicAdd(acc + 1, 0.0f);
            const float Nn = atomicAdd(acc + 2, 0.0f);
            out[0] = L / (float)B_N;
            out[1] = Dm / (float)B_N;
            out[2] = (Nn / (float)(B_N - 1)) / (float)B_N;
        }
    }
}

// ---------------- Fallback path (small workspace): fp32 vector --------------
__global__ __launch_bounds__(256) void fb_norm(
    const float* __restrict__ A, const float* __restrict__ P,
    float* __restrict__ rna, float* __restrict__ rnp, float* __restrict__ acc)
{
    const int r = blockIdx.x;
    const float* src = blockIdx.y ? P : A;
    const int t = threadIdx.x;
    float ss = 0.f;
    for (int k = t; k < D_K; k += 256) { float v = src[(size_t)r * D_K + k]; ss += v * v; }
    #pragma unroll
    for (int off = 32; off; off >>= 1) ss += __shfl_down(ss, off, 64);
    __shared__ float sred[4];
    if ((t & 63) == 0) sred[t >> 6] = ss;
    __syncthreads();
    if (t == 0) {
        const float rn = rsqrtf(sred[0] + sred[1] + sred[2] + sred[3]);
        (blockIdx.y ? rnp : rna)[r] = rn;
    }
    if (blockIdx.x == 0 && blockIdx.y == 0 && t < 3) acc[t] = 0.0f;
}

__global__ __launch_bounds__(256) void fb_main(
    const float* __restrict__ A, const float* __restrict__ P,
    const float* __restrict__ rna, const float* __restrict__ rnp,
    float* __restrict__ acc)
{
    __shared__ float sa[D_K];
    __shared__ float red[12];
    const int i = blockIdx.x;
    const int t = threadIdx.x;
    const float rn = rna[i];
    for (int k = t; k < D_K; k += 256) sa[k] = A[(size_t)i * D_K + k] * rn;
    __syncthreads();
    const int w = t >> 6, lane = t & 63;
    float we = 0.f, wsum = 0.f, wd = 0.f;
    for (int j = w; j < B_N; j += 4) {
        float dot = 0.f;
        const float* p = P + (size_t)j * D_K;
        for (int k = lane; k < D_K; k += 64) dot += sa[k] * p[k];
        #pragma unroll
        for (int off = 32; off; off >>= 1) dot += __shfl_xor(dot, off, 64);
        const float S = dot * rnp[j];
        we += __expf(S * 4.0f);
        wsum += S;
        if (j == i) wd = S;
    }
    if (lane == 0) { red[w] = we; red[4 + w] = wsum; red[8 + w] = wd; }
    __syncthreads();
    if (t == 0) {
        const float E  = red[0] + red[1] + red[2] + red[3];
        const float Sm = red[4] + red[5] + red[6] + red[7];
        const float Dd = red[8] + red[9] + red[10] + red[11];
        atomicAdd(acc + 0, __logf(E) - 4.0f * Dd);
        atomicAdd(acc + 1, Dd);
        atomicAdd(acc + 2, Sm - Dd);
    }
}

__global__ void fb_fin(const float* __restrict__ acc, float* __restrict__ out)
{
    out[0] = acc[0] / (float)B_N;
    out[1] = acc[1] / (float)B_N;
    out[2] = acc[2] / ((float)(B_N - 1) * (float)B_N);
}

// ---------------------------------------------------------------------------
extern "C" void kernel_launch(void* const* d_in, const int* in_sizes, int n_in,
                              void* d_out, int out_size, void* d_ws, size_t ws_size,
                              hipStream_t stream)
{
    const float* A = (const float*)d_in[0];
    const float* P = (const float*)d_in[1];
    float* out = (float*)d_out;
    char* ws = (char*)d_ws;

    const size_t AF8_OFF  = 0;
    const size_t PF8_OFF  = AF8_OFF + (size_t)B_N * KPAD;
    const size_t REXP_OFF = PF8_OFF + (size_t)B_N * KPAD;
    const size_t RSUM_OFF = REXP_OFF + (size_t)B_N * sizeof(float);
    const size_t DIAG_OFF = RSUM_OFF + (size_t)B_N * sizeof(float);
    const size_t ACC_OFF  = DIAG_OFF + (size_t)B_N * sizeof(float);
    const size_t MAIN_REQ = ACC_OFF + 16;

    if (ws_size >= MAIN_REQ) {
        unsigned char* Af8 = (unsigned char*)(ws + AF8_OFF);
        unsigned char* Pf8 = (unsigned char*)(ws + PF8_OFF);
        float* rowexp = (float*)(ws + REXP_OFF);
        float* rowsum = (float*)(ws + RSUM_OFF);
        float* diag   = (float*)(ws + DIAG_OFF);
        float* acc    = (float*)(ws + ACC_OFF);

        normalize_kernel<<<dim3(B_N / 8, 2), 256, 0, stream>>>(A, P, Af8, Pf8,
                                                               rowexp, rowsum, acc);
        gemm_fused_kernel<<<dim3(B_N / BM, COL_CHUNKS), 256, 0, stream>>>(
            Af8, Pf8, rowexp, rowsum, diag);
        finalize_kernel<<<FIN_BLOCKS, 256, 0, stream>>>(rowexp, rowsum, diag, acc, out);
    } else {
        // slow-but-correct fp32 fallback (needs ~96 KB ws)
        float* rna = (float*)ws;
        float* rnp = rna + B_N;
        float* acc = rnp + B_N;
        fb_norm<<<dim3(B_N, 2), 256, 0, stream>>>(A, P, rna, rnp, acc);
        fb_main<<<B_N, 256, 0, stream>>>(A, P, rna, rnp, acc);
        fb_fin<<<1, 1, 0, stream>>>(acc, out);
    }
}